// Round 8
// baseline (6627.503 us; speedup 1.0000x reference)
//
#include <hip/hip_runtime.h>
#include <hip/hip_bf16.h>
#include <math.h>

#define HID 64

// ---------------- CSR build ----------------

__global__ void count_kernel(const int* __restrict__ dst, int* __restrict__ cnt, int E, int N) {
    int e = blockIdx.x * blockDim.x + threadIdx.x;
    if (e < E) {
        int d = dst[e];
        if ((unsigned)d < (unsigned)N) atomicAdd(&cnt[d], 1);
    }
}

__global__ void dinv_kernel(const int* __restrict__ cnt, float* __restrict__ dinv, int n) {
    int i = blockIdx.x * blockDim.x + threadIdx.x;
    if (i < n) {
        float deg = (float)(cnt[i] + 1);   // +1 self loop
        dinv[i] = rsqrtf(deg);
    }
}

// two-level scan: A) per-chunk exclusive scan + chunk totals, B) scan chunk totals, C) add back
__global__ __launch_bounds__(1024) void scanA_kernel(const int* __restrict__ cnt,
        int* __restrict__ offs, int* __restrict__ bsum, int n) {
    __shared__ int buf[1024];
    int tid = threadIdx.x;
    int i = blockIdx.x * 1024 + tid;
    int v = (i < n) ? cnt[i] : 0;
    buf[tid] = v;
    __syncthreads();
    for (int off = 1; off < 1024; off <<= 1) {
        int t = (tid >= off) ? buf[tid - off] : 0;
        __syncthreads();
        buf[tid] += t;
        __syncthreads();
    }
    if (i < n) offs[i] = buf[tid] - v;          // exclusive within chunk
    if (tid == 1023) bsum[blockIdx.x] = buf[1023];
}

__global__ __launch_bounds__(1024) void scanB_kernel(int* __restrict__ bsum, int nb) {
    __shared__ int buf[1024];
    int tid = threadIdx.x;
    int v = (tid < nb) ? bsum[tid] : 0;
    buf[tid] = v;
    __syncthreads();
    for (int off = 1; off < 1024; off <<= 1) {
        int t = (tid >= off) ? buf[tid - off] : 0;
        __syncthreads();
        buf[tid] += t;
        __syncthreads();
    }
    if (tid < nb) bsum[tid] = buf[tid] - v;     // exclusive
    if (tid == nb - 1) bsum[nb] = buf[tid];     // total
}

__global__ __launch_bounds__(1024) void scanC_kernel(int* __restrict__ offs,
        const int* __restrict__ bsum, int n, int nb) {
    int i = blockIdx.x * 1024 + threadIdx.x;
    if (i < n) offs[i] += bsum[i >> 10];
    if (i == 0) offs[n] = bsum[nb];
}

// packed edge record: {src, norm}
__global__ void fill_kernel(const int* __restrict__ src, const int* __restrict__ dst,
                            const int* __restrict__ offs, int* __restrict__ cursor,
                            const float* __restrict__ dinv,
                            int2* __restrict__ pack, int E, int N) {
    int e = blockIdx.x * blockDim.x + threadIdx.x;
    if (e < E) {
        int s = src[e], d = dst[e];
        if ((unsigned)s < (unsigned)N && (unsigned)d < (unsigned)N) {
            int pos = atomicAdd(&cursor[d], 1);
            int j = offs[d] + pos;
            if ((unsigned)j < (unsigned)E)
                pack[j] = make_int2(s, __float_as_int(dinv[s] * dinv[d]));
        }
    }
}

// ---------------- lin1: h0 = relu(x @ W1 + b1), [n,512]@[512,64] ----------------

__global__ __launch_bounds__(256) void lin1_kernel(const float* __restrict__ x,
        const float* __restrict__ W, const float* __restrict__ b,
        float* __restrict__ out, int n) {
    const int BM = 64, BK = 32;
    __shared__ float As[BM][BK + 1];
    __shared__ float Ws[BK][64];
    int tid = threadIdx.x;
    int row0 = blockIdx.x * BM;
    int tx = tid & 15, ty = tid >> 4;
    float acc[4][4] = {};

    for (int k0 = 0; k0 < 512; k0 += BK) {
        {
            int r = tid >> 3, c4 = tid & 7;
            #pragma unroll
            for (int rr = 0; rr < 2; rr++) {
                int row = row0 + r + rr * 32;
                float4 v = make_float4(0.f, 0.f, 0.f, 0.f);
                if (row < n) v = *(const float4*)&x[(size_t)row * 512 + k0 + c4 * 4];
                As[r + rr * 32][c4 * 4 + 0] = v.x;
                As[r + rr * 32][c4 * 4 + 1] = v.y;
                As[r + rr * 32][c4 * 4 + 2] = v.z;
                As[r + rr * 32][c4 * 4 + 3] = v.w;
            }
        }
        {
            int r = tid >> 4, c4 = tid & 15;
            #pragma unroll
            for (int rr = 0; rr < 2; rr++) {
                float4 v = *(const float4*)&W[(size_t)(k0 + r + rr * 16) * 64 + c4 * 4];
                *(float4*)&Ws[r + rr * 16][c4 * 4] = v;
            }
        }
        __syncthreads();
        #pragma unroll
        for (int kk = 0; kk < BK; kk++) {
            float a0 = As[ty * 4 + 0][kk];
            float a1 = As[ty * 4 + 1][kk];
            float a2 = As[ty * 4 + 2][kk];
            float a3 = As[ty * 4 + 3][kk];
            float4 w = *(float4*)&Ws[kk][tx * 4];
            acc[0][0] += a0 * w.x; acc[0][1] += a0 * w.y; acc[0][2] += a0 * w.z; acc[0][3] += a0 * w.w;
            acc[1][0] += a1 * w.x; acc[1][1] += a1 * w.y; acc[1][2] += a1 * w.z; acc[1][3] += a1 * w.w;
            acc[2][0] += a2 * w.x; acc[2][1] += a2 * w.y; acc[2][2] += a2 * w.z; acc[2][3] += a2 * w.w;
            acc[3][0] += a3 * w.x; acc[3][1] += a3 * w.y; acc[3][2] += a3 * w.z; acc[3][3] += a3 * w.w;
        }
        __syncthreads();
    }
    #pragma unroll
    for (int i = 0; i < 4; i++) {
        int row = row0 + ty * 4 + i;
        if (row < n) {
            #pragma unroll
            for (int j = 0; j < 4; j++) {
                int col = tx * 4 + j;
                float v = acc[i][j] + b[col];
                out[(size_t)row * 64 + col] = fmaxf(v, 0.f);
            }
        }
    }
}

// ---------------- fused GCNII layer ----------------
// 4 waves/block, 4 nodes/wave (4 lane-groups x 16 lanes, float4 per lane).
// Phase 1: gather (4x unroll) + x0 residual, all in gather layout.
// Transpose z into zt[k] = {z0[k],z1[k],z2[k],z3[k]} via 4 ds_write_b32.
// Phase 2: mv[nn] = sum_k zt[k][nn] * W[k][lane]  (broadcast b128 + b32 + 4 FMA per k).
// No persistent W registers -> low VGPR -> high occupancy.

__global__ __launch_bounds__(256) void layer_kernel(
        const float4* __restrict__ h4, const float4* __restrict__ x04,
        float* __restrict__ h_out,
        const int* __restrict__ rowptr, const int2* __restrict__ pack,
        const float* __restrict__ dinv,
        const float* __restrict__ W, float beta, int n) {
    __shared__ float Wsh[HID * HID];          // 16 KB
    __shared__ float4 zt[4][HID];             // 4 KB: [wave][k] = z of 4 nodes at feature k
    int tid = threadIdx.x;
    for (int i = tid; i < HID * HID / 4; i += 256)
        ((float4*)Wsh)[i] = ((const float4*)W)[i];
    __syncthreads();
    int lane = tid & 63, wave = tid >> 6;
    int g = lane >> 4;        // node within wave
    int c = lane & 15;        // float4 slot within row
    float omb = 1.0f - beta;

    int base = (blockIdx.x * 4 + wave) * 4;
    if (base >= n) return;

    // ---- phase 1: gather + residual (group g owns node base+g) ----
    int node = base + g;
    float4 acc = make_float4(0.f, 0.f, 0.f, 0.f);
    if (node < n) {
        float di = dinv[node];
        float d2 = di * di;
        float4 self = h4[(size_t)node * 16 + c];
        acc.x = d2 * self.x; acc.y = d2 * self.y;
        acc.z = d2 * self.z; acc.w = d2 * self.w;
        int e0 = rowptr[node];
        int deg = rowptr[node + 1] - e0;
        int e = 0;
        for (; e + 4 <= deg; e += 4) {
            int2 p0 = pack[e0 + e + 0];
            int2 p1 = pack[e0 + e + 1];
            int2 p2 = pack[e0 + e + 2];
            int2 p3 = pack[e0 + e + 3];
            float4 v0 = h4[(size_t)p0.x * 16 + c];
            float4 v1 = h4[(size_t)p1.x * 16 + c];
            float4 v2 = h4[(size_t)p2.x * 16 + c];
            float4 v3 = h4[(size_t)p3.x * 16 + c];
            float n0 = __int_as_float(p0.y), n1 = __int_as_float(p1.y);
            float n2 = __int_as_float(p2.y), n3 = __int_as_float(p3.y);
            acc.x += n0 * v0.x + n1 * v1.x + n2 * v2.x + n3 * v3.x;
            acc.y += n0 * v0.y + n1 * v1.y + n2 * v2.y + n3 * v3.y;
            acc.z += n0 * v0.z + n1 * v1.z + n2 * v2.z + n3 * v3.z;
            acc.w += n0 * v0.w + n1 * v1.w + n2 * v2.w + n3 * v3.w;
        }
        for (; e < deg; e++) {
            int2 p = pack[e0 + e];
            float4 v = h4[(size_t)p.x * 16 + c];
            float nv = __int_as_float(p.y);
            acc.x += nv * v.x; acc.y += nv * v.y;
            acc.z += nv * v.z; acc.w += nv * v.w;
        }
        float4 x0v = x04[(size_t)node * 16 + c];
        acc.x = 0.5f * acc.x + 0.5f * x0v.x;   // ALPHA = 0.5
        acc.y = 0.5f * acc.y + 0.5f * x0v.y;
        acc.z = 0.5f * acc.z + 0.5f * x0v.z;
        acc.w = 0.5f * acc.w + 0.5f * x0v.w;
    }
    // ---- transpose z into zt (wave-internal, DS ops in program order) ----
    {
        float* zf = (float*)&zt[wave][0];
        zf[(4 * c + 0) * 4 + g] = acc.x;
        zf[(4 * c + 1) * 4 + g] = acc.y;
        zf[(4 * c + 2) * 4 + g] = acc.z;
        zf[(4 * c + 3) * 4 + g] = acc.w;
    }
    // ---- phase 2: matvec for 4 nodes at once, lane = output feature ----
    float4 mv = make_float4(0.f, 0.f, 0.f, 0.f);
    #pragma unroll
    for (int k = 0; k < HID; k++) {
        float4 zk = zt[wave][k];              // broadcast read
        float wk = Wsh[k * HID + lane];       // conflict-free
        mv.x += zk.x * wk; mv.y += zk.y * wk;
        mv.z += zk.z * wk; mv.w += zk.w * wk;
    }
    // ---- epilogue: y = (1-b) z + b mv, relu ----
    float4 zrow = zt[wave][lane];             // z of 4 nodes at feature `lane`
    float4 y;
    y.x = fmaxf(omb * zrow.x + beta * mv.x, 0.f);
    y.y = fmaxf(omb * zrow.y + beta * mv.y, 0.f);
    y.z = fmaxf(omb * zrow.z + beta * mv.z, 0.f);
    y.w = fmaxf(omb * zrow.w + beta * mv.w, 0.f);
    if (base + 0 < n) h_out[(size_t)(base + 0) * HID + lane] = y.x;
    if (base + 1 < n) h_out[(size_t)(base + 1) * HID + lane] = y.y;
    if (base + 2 < n) h_out[(size_t)(base + 2) * HID + lane] = y.z;
    if (base + 3 < n) h_out[(size_t)(base + 3) * HID + lane] = y.w;
}

// ---------------- lin2 + log_softmax ----------------

__global__ __launch_bounds__(256) void out_kernel(const float* __restrict__ h,
        const float* __restrict__ W2, const float* __restrict__ b2,
        float* __restrict__ out, int n) {
    __shared__ float W2s[64 * 40];
    alignas(16) __shared__ float hs[4][64];
    int tid = threadIdx.x;
    for (int i = tid; i < 64 * 40; i += 256) W2s[i] = W2[i];
    __syncthreads();
    int lane = tid & 63, wave = tid >> 6;
    int c = (lane < 40) ? lane : 0;
    float wc[64];
    #pragma unroll
    for (int k = 0; k < 64; k++) wc[k] = W2s[k * 40 + c];
    float bias = b2[c];
    for (int i = blockIdx.x * 4 + wave; i < n; i += gridDim.x * 4) {
        hs[wave][lane] = h[(size_t)i * 64 + lane];
        float o = bias;
        #pragma unroll
        for (int k4 = 0; k4 < 16; k4++) {
            float4 hb = *(float4*)&hs[wave][k4 * 4];
            o += hb.x * wc[k4 * 4 + 0] + hb.y * wc[k4 * 4 + 1]
               + hb.z * wc[k4 * 4 + 2] + hb.w * wc[k4 * 4 + 3];
        }
        float val = (lane < 40) ? o : -INFINITY;
        float m = val;
        #pragma unroll
        for (int d = 1; d < 64; d <<= 1) m = fmaxf(m, __shfl_xor(m, d, 64));
        float e = (lane < 40) ? expf(o - m) : 0.f;
        float s = e;
        #pragma unroll
        for (int d = 1; d < 64; d <<= 1) s += __shfl_xor(s, d, 64);
        if (lane < 40) out[(size_t)i * 40 + lane] = (o - m) - logf(s);
    }
}

__global__ void zero_out_kernel(float* __restrict__ out, int n) {
    int i = blockIdx.x * blockDim.x + threadIdx.x;
    if (i < n) out[i] = 0.f;
}

// ---------------- launcher ----------------

extern "C" void kernel_launch(void* const* d_in, const int* in_sizes, int n_in,
                              void* d_out, int out_size, void* d_ws, size_t ws_size,
                              hipStream_t stream) {
    const float* x    = (const float*)d_in[0];
    const int*   ei   = (const int*)d_in[1];     // int32
    const float* W1   = (const float*)d_in[2];
    const float* b1   = (const float*)d_in[3];
    const float* Wc   = (const float*)d_in[4];
    const float* W2   = (const float*)d_in[5];
    const float* b2   = (const float*)d_in[6];
    float* outp = (float*)d_out;

    const int N = in_sizes[0] / 512;         // 50000
    const int E = in_sizes[1] / 2;           // 800000
    const int L = in_sizes[4] / (HID * HID); // 64

    const int* src = ei;
    const int* dst = ei + E;
    const int NB_SCAN = (N + 1023) / 1024;   // 49

    size_t need = ((size_t)N * HID * 3 + (size_t)N * 3 + (N + 1) + (NB_SCAN + 1)) * 4
                + (size_t)E * 8;
    if (ws_size < need) {
        zero_out_kernel<<<(out_size + 255) / 256, 256, 0, stream>>>(outp, out_size);
        return;
    }
    char* p = (char*)d_ws;
    float* hA   = (float*)p;            p += (size_t)N * HID * 4;
    float* hB   = (float*)p;            p += (size_t)N * HID * 4;
    float* x0b  = (float*)p;            p += (size_t)N * HID * 4;
    float* dinv = (float*)p;            p += (size_t)N * 4;
    int2*  pack = (int2*)p;             p += (size_t)E * 8;
    int*   cnt  = (int*)p;              p += (size_t)N * 4;
    int*   offs = (int*)p;              p += (size_t)(N + 1) * 4;
    int*   cursor = (int*)p;            p += (size_t)N * 4;
    int*   bsum = (int*)p;              p += (size_t)(NB_SCAN + 1) * 4;

    hipMemsetAsync(cnt, 0, (size_t)N * 4, stream);
    hipMemsetAsync(cursor, 0, (size_t)N * 4, stream);

    count_kernel<<<(E + 255) / 256, 256, 0, stream>>>(dst, cnt, E, N);
    dinv_kernel<<<(N + 255) / 256, 256, 0, stream>>>(cnt, dinv, N);
    scanA_kernel<<<NB_SCAN, 1024, 0, stream>>>(cnt, offs, bsum, N);
    scanB_kernel<<<1, 1024, 0, stream>>>(bsum, NB_SCAN);
    scanC_kernel<<<NB_SCAN, 1024, 0, stream>>>(offs, bsum, N, NB_SCAN);
    fill_kernel<<<(E + 255) / 256, 256, 0, stream>>>(src, dst, offs, cursor, dinv,
                                                     pack, E, N);

    lin1_kernel<<<(N + 63) / 64, 256, 0, stream>>>(x, W1, b1, x0b, N);

    int nblocks = (N + 15) / 16;            // 16 nodes per block
    float* cur_in = x0b;
    float* cur_out = hA;
    for (int l = 0; l < L; l++) {
        float beta = log1pf(1.0f / (float)(l + 1));
        layer_kernel<<<nblocks, 256, 0, stream>>>((const float4*)cur_in, (const float4*)x0b,
                                                  cur_out, offs, pack, dinv,
                                                  Wc + (size_t)l * HID * HID, beta, N);
        float* nxt = (cur_out == hA) ? hB : hA;
        cur_in = cur_out;
        cur_out = nxt;
    }

    out_kernel<<<1024, 256, 0, stream>>>(cur_in, W2, b2, outp, N);
}

// Round 9
// 2548.785 us; speedup vs baseline: 2.6003x; 2.6003x over previous
//
#include <hip/hip_runtime.h>
#include <hip/hip_bf16.h>
#include <math.h>

#define HID 64

// ---------------- CSR build ----------------

__global__ void count_kernel(const int* __restrict__ dst, int* __restrict__ cnt, int E, int N) {
    int e = blockIdx.x * blockDim.x + threadIdx.x;
    if (e < E) {
        int d = dst[e];
        if ((unsigned)d < (unsigned)N) atomicAdd(&cnt[d], 1);
    }
}

__global__ void dinv_kernel(const int* __restrict__ cnt, float* __restrict__ dinv, int n) {
    int i = blockIdx.x * blockDim.x + threadIdx.x;
    if (i < n) {
        float deg = (float)(cnt[i] + 1);   // +1 self loop
        dinv[i] = rsqrtf(deg);
    }
}

// two-level scan: A) per-chunk exclusive scan + chunk totals, B) scan chunk totals, C) add back
__global__ __launch_bounds__(1024) void scanA_kernel(const int* __restrict__ cnt,
        int* __restrict__ offs, int* __restrict__ bsum, int n) {
    __shared__ int buf[1024];
    int tid = threadIdx.x;
    int i = blockIdx.x * 1024 + tid;
    int v = (i < n) ? cnt[i] : 0;
    buf[tid] = v;
    __syncthreads();
    for (int off = 1; off < 1024; off <<= 1) {
        int t = (tid >= off) ? buf[tid - off] : 0;
        __syncthreads();
        buf[tid] += t;
        __syncthreads();
    }
    if (i < n) offs[i] = buf[tid] - v;          // exclusive within chunk
    if (tid == 1023) bsum[blockIdx.x] = buf[1023];
}

__global__ __launch_bounds__(1024) void scanB_kernel(int* __restrict__ bsum, int nb) {
    __shared__ int buf[1024];
    int tid = threadIdx.x;
    int v = (tid < nb) ? bsum[tid] : 0;
    buf[tid] = v;
    __syncthreads();
    for (int off = 1; off < 1024; off <<= 1) {
        int t = (tid >= off) ? buf[tid - off] : 0;
        __syncthreads();
        buf[tid] += t;
        __syncthreads();
    }
    if (tid < nb) bsum[tid] = buf[tid] - v;     // exclusive
    if (tid == nb - 1) bsum[nb] = buf[tid];     // total
}

__global__ __launch_bounds__(1024) void scanC_kernel(int* __restrict__ offs,
        const int* __restrict__ bsum, int n, int nb) {
    int i = blockIdx.x * 1024 + threadIdx.x;
    if (i < n) offs[i] += bsum[i >> 10];
    if (i == 0) offs[n] = bsum[nb];
}

// packed edge record: {src, norm}
__global__ void fill_kernel(const int* __restrict__ src, const int* __restrict__ dst,
                            const int* __restrict__ offs, int* __restrict__ cursor,
                            const float* __restrict__ dinv,
                            int2* __restrict__ pack, int E, int N) {
    int e = blockIdx.x * blockDim.x + threadIdx.x;
    if (e < E) {
        int s = src[e], d = dst[e];
        if ((unsigned)s < (unsigned)N && (unsigned)d < (unsigned)N) {
            int pos = atomicAdd(&cursor[d], 1);
            int j = offs[d] + pos;
            if ((unsigned)j < (unsigned)E)
                pack[j] = make_int2(s, __float_as_int(dinv[s] * dinv[d]));
        }
    }
}

// ---------------- lin1: h0 = relu(x @ W1 + b1), [n,512]@[512,64] ----------------

__global__ __launch_bounds__(256) void lin1_kernel(const float* __restrict__ x,
        const float* __restrict__ W, const float* __restrict__ b,
        float* __restrict__ out, int n) {
    const int BM = 64, BK = 32;
    __shared__ float As[BM][BK + 1];
    __shared__ float Ws[BK][64];
    int tid = threadIdx.x;
    int row0 = blockIdx.x * BM;
    int tx = tid & 15, ty = tid >> 4;
    float acc[4][4] = {};

    for (int k0 = 0; k0 < 512; k0 += BK) {
        {
            int r = tid >> 3, c4 = tid & 7;
            #pragma unroll
            for (int rr = 0; rr < 2; rr++) {
                int row = row0 + r + rr * 32;
                float4 v = make_float4(0.f, 0.f, 0.f, 0.f);
                if (row < n) v = *(const float4*)&x[(size_t)row * 512 + k0 + c4 * 4];
                As[r + rr * 32][c4 * 4 + 0] = v.x;
                As[r + rr * 32][c4 * 4 + 1] = v.y;
                As[r + rr * 32][c4 * 4 + 2] = v.z;
                As[r + rr * 32][c4 * 4 + 3] = v.w;
            }
        }
        {
            int r = tid >> 4, c4 = tid & 15;
            #pragma unroll
            for (int rr = 0; rr < 2; rr++) {
                float4 v = *(const float4*)&W[(size_t)(k0 + r + rr * 16) * 64 + c4 * 4];
                *(float4*)&Ws[r + rr * 16][c4 * 4] = v;
            }
        }
        __syncthreads();
        #pragma unroll
        for (int kk = 0; kk < BK; kk++) {
            float a0 = As[ty * 4 + 0][kk];
            float a1 = As[ty * 4 + 1][kk];
            float a2 = As[ty * 4 + 2][kk];
            float a3 = As[ty * 4 + 3][kk];
            float4 w = *(float4*)&Ws[kk][tx * 4];
            acc[0][0] += a0 * w.x; acc[0][1] += a0 * w.y; acc[0][2] += a0 * w.z; acc[0][3] += a0 * w.w;
            acc[1][0] += a1 * w.x; acc[1][1] += a1 * w.y; acc[1][2] += a1 * w.z; acc[1][3] += a1 * w.w;
            acc[2][0] += a2 * w.x; acc[2][1] += a2 * w.y; acc[2][2] += a2 * w.z; acc[2][3] += a2 * w.w;
            acc[3][0] += a3 * w.x; acc[3][1] += a3 * w.y; acc[3][2] += a3 * w.z; acc[3][3] += a3 * w.w;
        }
        __syncthreads();
    }
    #pragma unroll
    for (int i = 0; i < 4; i++) {
        int row = row0 + ty * 4 + i;
        if (row < n) {
            #pragma unroll
            for (int j = 0; j < 4; j++) {
                int col = tx * 4 + j;
                float v = acc[i][j] + b[col];
                out[(size_t)row * 64 + col] = fmaxf(v, 0.f);
            }
        }
    }
}

// ---------------- fused GCNII layer ----------------
// 4 waves/block, 4 nodes/wave (4 lane-groups x 16 lanes, float4 per lane), grid-stride.
// Phase 1: gather (4x unroll) + x0 residual, all in gather layout.
// Transpose z into zt[k] = {z0[k],z1[k],z2[k],z3[k]} via 4 ds_write_b32.
// Phase 2: mv[nn] = sum_k zt[k][nn] * W[k][lane], UNROLL CAPPED AT 8 to bound VGPR.

__global__ __launch_bounds__(256) void layer_kernel(
        const float4* __restrict__ h4, const float4* __restrict__ x04,
        float* __restrict__ h_out,
        const int* __restrict__ rowptr, const int2* __restrict__ pack,
        const float* __restrict__ dinv,
        const float* __restrict__ W, float beta, int n) {
    __shared__ float Wsh[HID * HID];          // 16 KB
    __shared__ float4 zt[4][HID];             // 4 KB: [wave][k] = z of 4 nodes at feature k
    int tid = threadIdx.x;
    for (int i = tid; i < HID * HID / 4; i += 256)
        ((float4*)Wsh)[i] = ((const float4*)W)[i];
    __syncthreads();
    int lane = tid & 63, wave = tid >> 6;
    int g = lane >> 4;        // node within wave
    int c = lane & 15;        // float4 slot within row
    float omb = 1.0f - beta;

    for (int base = (blockIdx.x * 4 + wave) * 4; base < n; base += gridDim.x * 16) {
        // ---- phase 1: gather + residual (group g owns node base+g) ----
        int node = base + g;
        float4 acc = make_float4(0.f, 0.f, 0.f, 0.f);
        if (node < n) {
            float di = dinv[node];
            float d2 = di * di;
            float4 self = h4[(size_t)node * 16 + c];
            acc.x = d2 * self.x; acc.y = d2 * self.y;
            acc.z = d2 * self.z; acc.w = d2 * self.w;
            int e0 = rowptr[node];
            int deg = rowptr[node + 1] - e0;
            int e = 0;
            for (; e + 4 <= deg; e += 4) {
                int2 p0 = pack[e0 + e + 0];
                int2 p1 = pack[e0 + e + 1];
                int2 p2 = pack[e0 + e + 2];
                int2 p3 = pack[e0 + e + 3];
                float4 v0 = h4[(size_t)p0.x * 16 + c];
                float4 v1 = h4[(size_t)p1.x * 16 + c];
                float4 v2 = h4[(size_t)p2.x * 16 + c];
                float4 v3 = h4[(size_t)p3.x * 16 + c];
                float n0 = __int_as_float(p0.y), n1 = __int_as_float(p1.y);
                float n2 = __int_as_float(p2.y), n3 = __int_as_float(p3.y);
                acc.x += n0 * v0.x + n1 * v1.x + n2 * v2.x + n3 * v3.x;
                acc.y += n0 * v0.y + n1 * v1.y + n2 * v2.y + n3 * v3.y;
                acc.z += n0 * v0.z + n1 * v1.z + n2 * v2.z + n3 * v3.z;
                acc.w += n0 * v0.w + n1 * v1.w + n2 * v2.w + n3 * v3.w;
            }
            for (; e < deg; e++) {
                int2 p = pack[e0 + e];
                float4 v = h4[(size_t)p.x * 16 + c];
                float nv = __int_as_float(p.y);
                acc.x += nv * v.x; acc.y += nv * v.y;
                acc.z += nv * v.z; acc.w += nv * v.w;
            }
            float4 x0v = x04[(size_t)node * 16 + c];
            acc.x = 0.5f * acc.x + 0.5f * x0v.x;   // ALPHA = 0.5
            acc.y = 0.5f * acc.y + 0.5f * x0v.y;
            acc.z = 0.5f * acc.z + 0.5f * x0v.z;
            acc.w = 0.5f * acc.w + 0.5f * x0v.w;
        }
        // ---- transpose z into zt (wave-internal, DS ops in program order) ----
        {
            float* zf = (float*)&zt[wave][0];
            zf[(4 * c + 0) * 4 + g] = acc.x;
            zf[(4 * c + 1) * 4 + g] = acc.y;
            zf[(4 * c + 2) * 4 + g] = acc.z;
            zf[(4 * c + 3) * 4 + g] = acc.w;
        }
        // ---- phase 2: matvec for 4 nodes at once, lane = output feature ----
        float4 mv = make_float4(0.f, 0.f, 0.f, 0.f);
        #pragma unroll 8
        for (int k = 0; k < HID; k++) {
            float4 zk = zt[wave][k];              // broadcast read (cheap: same addr wave-wide)
            float wk = Wsh[k * HID + lane];       // 256B row read, conflict-free
            mv.x += zk.x * wk; mv.y += zk.y * wk;
            mv.z += zk.z * wk; mv.w += zk.w * wk;
        }
        // ---- epilogue: y = (1-b) z + b mv, relu ----
        float4 zrow = zt[wave][lane];             // z of 4 nodes at feature `lane`
        float4 y;
        y.x = fmaxf(omb * zrow.x + beta * mv.x, 0.f);
        y.y = fmaxf(omb * zrow.y + beta * mv.y, 0.f);
        y.z = fmaxf(omb * zrow.z + beta * mv.z, 0.f);
        y.w = fmaxf(omb * zrow.w + beta * mv.w, 0.f);
        if (base + 0 < n) h_out[(size_t)(base + 0) * HID + lane] = y.x;
        if (base + 1 < n) h_out[(size_t)(base + 1) * HID + lane] = y.y;
        if (base + 2 < n) h_out[(size_t)(base + 2) * HID + lane] = y.z;
        if (base + 3 < n) h_out[(size_t)(base + 3) * HID + lane] = y.w;
    }
}

// ---------------- lin2 + log_softmax ----------------

__global__ __launch_bounds__(256) void out_kernel(const float* __restrict__ h,
        const float* __restrict__ W2, const float* __restrict__ b2,
        float* __restrict__ out, int n) {
    __shared__ float W2s[64 * 40];
    alignas(16) __shared__ float hs[4][64];
    int tid = threadIdx.x;
    for (int i = tid; i < 64 * 40; i += 256) W2s[i] = W2[i];
    __syncthreads();
    int lane = tid & 63, wave = tid >> 6;
    int c = (lane < 40) ? lane : 0;
    float wc[64];
    #pragma unroll
    for (int k = 0; k < 64; k++) wc[k] = W2s[k * 40 + c];
    float bias = b2[c];
    for (int i = blockIdx.x * 4 + wave; i < n; i += gridDim.x * 4) {
        hs[wave][lane] = h[(size_t)i * 64 + lane];
        float o = bias;
        #pragma unroll
        for (int k4 = 0; k4 < 16; k4++) {
            float4 hb = *(float4*)&hs[wave][k4 * 4];
            o += hb.x * wc[k4 * 4 + 0] + hb.y * wc[k4 * 4 + 1]
               + hb.z * wc[k4 * 4 + 2] + hb.w * wc[k4 * 4 + 3];
        }
        float val = (lane < 40) ? o : -INFINITY;
        float m = val;
        #pragma unroll
        for (int d = 1; d < 64; d <<= 1) m = fmaxf(m, __shfl_xor(m, d, 64));
        float e = (lane < 40) ? expf(o - m) : 0.f;
        float s = e;
        #pragma unroll
        for (int d = 1; d < 64; d <<= 1) s += __shfl_xor(s, d, 64);
        if (lane < 40) out[(size_t)i * 40 + lane] = (o - m) - logf(s);
    }
}

__global__ void zero_out_kernel(float* __restrict__ out, int n) {
    int i = blockIdx.x * blockDim.x + threadIdx.x;
    if (i < n) out[i] = 0.f;
}

// ---------------- launcher ----------------

extern "C" void kernel_launch(void* const* d_in, const int* in_sizes, int n_in,
                              void* d_out, int out_size, void* d_ws, size_t ws_size,
                              hipStream_t stream) {
    const float* x    = (const float*)d_in[0];
    const int*   ei   = (const int*)d_in[1];     // int32
    const float* W1   = (const float*)d_in[2];
    const float* b1   = (const float*)d_in[3];
    const float* Wc   = (const float*)d_in[4];
    const float* W2   = (const float*)d_in[5];
    const float* b2   = (const float*)d_in[6];
    float* outp = (float*)d_out;

    const int N = in_sizes[0] / 512;         // 50000
    const int E = in_sizes[1] / 2;           // 800000
    const int L = in_sizes[4] / (HID * HID); // 64

    const int* src = ei;
    const int* dst = ei + E;
    const int NB_SCAN = (N + 1023) / 1024;   // 49

    size_t need = ((size_t)N * HID * 3 + (size_t)N * 3 + (N + 1) + (NB_SCAN + 1)) * 4
                + (size_t)E * 8;
    if (ws_size < need) {
        zero_out_kernel<<<(out_size + 255) / 256, 256, 0, stream>>>(outp, out_size);
        return;
    }
    char* p = (char*)d_ws;
    float* hA   = (float*)p;            p += (size_t)N * HID * 4;
    float* hB   = (float*)p;            p += (size_t)N * HID * 4;
    float* x0b  = (float*)p;            p += (size_t)N * HID * 4;
    float* dinv = (float*)p;            p += (size_t)N * 4;
    int2*  pack = (int2*)p;             p += (size_t)E * 8;
    int*   cnt  = (int*)p;              p += (size_t)N * 4;
    int*   offs = (int*)p;              p += (size_t)(N + 1) * 4;
    int*   cursor = (int*)p;            p += (size_t)N * 4;
    int*   bsum = (int*)p;              p += (size_t)(NB_SCAN + 1) * 4;

    hipMemsetAsync(cnt, 0, (size_t)N * 4, stream);
    hipMemsetAsync(cursor, 0, (size_t)N * 4, stream);

    count_kernel<<<(E + 255) / 256, 256, 0, stream>>>(dst, cnt, E, N);
    dinv_kernel<<<(N + 255) / 256, 256, 0, stream>>>(cnt, dinv, N);
    scanA_kernel<<<NB_SCAN, 1024, 0, stream>>>(cnt, offs, bsum, N);
    scanB_kernel<<<1, 1024, 0, stream>>>(bsum, NB_SCAN);
    scanC_kernel<<<NB_SCAN, 1024, 0, stream>>>(offs, bsum, N, NB_SCAN);
    fill_kernel<<<(E + 255) / 256, 256, 0, stream>>>(src, dst, offs, cursor, dinv,
                                                     pack, E, N);

    lin1_kernel<<<(N + 63) / 64, 256, 0, stream>>>(x, W1, b1, x0b, N);

    // grid-stride: 2048 blocks, each handles multiple 16-node chunks (W staged once/block)
    float* cur_in = x0b;
    float* cur_out = hA;
    for (int l = 0; l < L; l++) {
        float beta = log1pf(1.0f / (float)(l + 1));
        layer_kernel<<<2048, 256, 0, stream>>>((const float4*)cur_in, (const float4*)x0b,
                                               cur_out, offs, pack, dinv,
                                               Wc + (size_t)l * HID * HID, beta, N);
        float* nxt = (cur_out == hA) ? hB : hA;
        cur_in = cur_out;
        cur_out = nxt;
    }

    out_kernel<<<1024, 256, 0, stream>>>(cur_in, W2, b2, outp, N);
}

// Round 11
// 2197.578 us; speedup vs baseline: 3.0158x; 1.1598x over previous
//
#include <hip/hip_runtime.h>
#include <hip/hip_bf16.h>
#include <hip/hip_fp16.h>
#include <math.h>

#define HID 64

union HU { __half h; unsigned short u; };
__device__ inline float h2f(unsigned short u) { HU x; x.u = u; return __half2float(x.h); }
__device__ inline unsigned short f2h(float f) { HU x; x.h = __float2half(f); return x.u; }

// ---------------- CSR build ----------------

__global__ void count_kernel(const int* __restrict__ dst, int* __restrict__ cnt, int E, int N) {
    int e = blockIdx.x * blockDim.x + threadIdx.x;
    if (e < E) {
        int d = dst[e];
        if ((unsigned)d < (unsigned)N) atomicAdd(&cnt[d], 1);
    }
}

__global__ void dinv_kernel(const int* __restrict__ cnt, float* __restrict__ dinv, int n) {
    int i = blockIdx.x * blockDim.x + threadIdx.x;
    if (i < n) {
        float deg = (float)(cnt[i] + 1);   // +1 self loop
        dinv[i] = rsqrtf(deg);
    }
}

// two-level scan
__global__ __launch_bounds__(1024) void scanA_kernel(const int* __restrict__ cnt,
        int* __restrict__ offs, int* __restrict__ bsum, int n) {
    __shared__ int buf[1024];
    int tid = threadIdx.x;
    int i = blockIdx.x * 1024 + tid;
    int v = (i < n) ? cnt[i] : 0;
    buf[tid] = v;
    __syncthreads();
    for (int off = 1; off < 1024; off <<= 1) {
        int t = (tid >= off) ? buf[tid - off] : 0;
        __syncthreads();
        buf[tid] += t;
        __syncthreads();
    }
    if (i < n) offs[i] = buf[tid] - v;
    if (tid == 1023) bsum[blockIdx.x] = buf[1023];
}

__global__ __launch_bounds__(1024) void scanB_kernel(int* __restrict__ bsum, int nb) {
    __shared__ int buf[1024];
    int tid = threadIdx.x;
    int v = (tid < nb) ? bsum[tid] : 0;
    buf[tid] = v;
    __syncthreads();
    for (int off = 1; off < 1024; off <<= 1) {
        int t = (tid >= off) ? buf[tid - off] : 0;
        __syncthreads();
        buf[tid] += t;
        __syncthreads();
    }
    if (tid < nb) bsum[tid] = buf[tid] - v;
    if (tid == nb - 1) bsum[nb] = buf[tid];
}

__global__ __launch_bounds__(1024) void scanC_kernel(int* __restrict__ offs,
        const int* __restrict__ bsum, int n, int nb) {
    int i = blockIdx.x * 1024 + threadIdx.x;
    if (i < n) offs[i] += bsum[i >> 10];
    if (i == 0) offs[n] = bsum[nb];
}

// packed edge record: {src, norm}
__global__ void fill_kernel(const int* __restrict__ src, const int* __restrict__ dst,
                            const int* __restrict__ offs, int* __restrict__ cursor,
                            const float* __restrict__ dinv,
                            int2* __restrict__ pack, int E, int N) {
    int e = blockIdx.x * blockDim.x + threadIdx.x;
    if (e < E) {
        int s = src[e], d = dst[e];
        if ((unsigned)s < (unsigned)N && (unsigned)d < (unsigned)N) {
            int pos = atomicAdd(&cursor[d], 1);
            int j = offs[d] + pos;
            if ((unsigned)j < (unsigned)E)
                pack[j] = make_int2(s, __float_as_int(dinv[s] * dinv[d]));
        }
    }
}

// ---------------- lin1: h0 = relu(x @ W1 + b1) ----------------
// register-prefetch double buffer: next k-tile global loads overlap current compute.
// outputs BOTH fp32 x0 (residual anchor) and fp16 h0 (layer input).

__global__ __launch_bounds__(256) void lin1_kernel(const float* __restrict__ x,
        const float* __restrict__ W, const float* __restrict__ b,
        float* __restrict__ out32, unsigned short* __restrict__ out16, int n) {
    const int BM = 64, BK = 32;
    __shared__ float As[BM][BK + 1];
    __shared__ float Ws[BK][64];
    int tid = threadIdx.x;
    int row0 = blockIdx.x * BM;
    int tx = tid & 15, ty = tid >> 4;
    float acc[4][4] = {};

    int ar = tid >> 3, ac4 = tid & 7;     // A: 2 float4 per thread
    int wr = tid >> 4, wc4 = tid & 15;    // W: 2 float4 per thread
    float4 a_pf[2], w_pf[2];

    // prologue: prefetch k0 = 0
    #pragma unroll
    for (int rr = 0; rr < 2; rr++) {
        int row = row0 + ar + rr * 32;
        a_pf[rr] = make_float4(0.f, 0.f, 0.f, 0.f);
        if (row < n) a_pf[rr] = *(const float4*)&x[(size_t)row * 512 + ac4 * 4];
        w_pf[rr] = *(const float4*)&W[(size_t)(wr + rr * 16) * 64 + wc4 * 4];
    }

    for (int k0 = 0; k0 < 512; k0 += BK) {
        // write prefetched tile to LDS
        #pragma unroll
        for (int rr = 0; rr < 2; rr++) {
            As[ar + rr * 32][ac4 * 4 + 0] = a_pf[rr].x;
            As[ar + rr * 32][ac4 * 4 + 1] = a_pf[rr].y;
            As[ar + rr * 32][ac4 * 4 + 2] = a_pf[rr].z;
            As[ar + rr * 32][ac4 * 4 + 3] = a_pf[rr].w;
            *(float4*)&Ws[wr + rr * 16][wc4 * 4] = w_pf[rr];
        }
        __syncthreads();
        // issue next-tile loads (overlap with compute below)
        int k1 = k0 + BK;
        if (k1 < 512) {
            #pragma unroll
            for (int rr = 0; rr < 2; rr++) {
                int row = row0 + ar + rr * 32;
                a_pf[rr] = make_float4(0.f, 0.f, 0.f, 0.f);
                if (row < n) a_pf[rr] = *(const float4*)&x[(size_t)row * 512 + k1 + ac4 * 4];
                w_pf[rr] = *(const float4*)&W[(size_t)(k1 + wr + rr * 16) * 64 + wc4 * 4];
            }
        }
        #pragma unroll
        for (int kk = 0; kk < BK; kk++) {
            float a0 = As[ty * 4 + 0][kk];
            float a1 = As[ty * 4 + 1][kk];
            float a2 = As[ty * 4 + 2][kk];
            float a3 = As[ty * 4 + 3][kk];
            float4 w = *(float4*)&Ws[kk][tx * 4];
            acc[0][0] += a0 * w.x; acc[0][1] += a0 * w.y; acc[0][2] += a0 * w.z; acc[0][3] += a0 * w.w;
            acc[1][0] += a1 * w.x; acc[1][1] += a1 * w.y; acc[1][2] += a1 * w.z; acc[1][3] += a1 * w.w;
            acc[2][0] += a2 * w.x; acc[2][1] += a2 * w.y; acc[2][2] += a2 * w.z; acc[2][3] += a2 * w.w;
            acc[3][0] += a3 * w.x; acc[3][1] += a3 * w.y; acc[3][2] += a3 * w.z; acc[3][3] += a3 * w.w;
        }
        __syncthreads();
    }
    #pragma unroll
    for (int i = 0; i < 4; i++) {
        int row = row0 + ty * 4 + i;
        if (row < n) {
            #pragma unroll
            for (int j = 0; j < 4; j++) {
                int col = tx * 4 + j;
                float v = fmaxf(acc[i][j] + b[col], 0.f);
                out32[(size_t)row * 64 + col] = v;
                out16[(size_t)row * 64 + col] = f2h(v);
            }
        }
    }
}

// ---------------- fused GCNII layer ----------------
// h stored fp16 (128B rows -> halved gather traffic); z/matvec/residual fp32.
// 4 waves/block, 4 nodes/wave (4 lane-groups x 16 lanes, ushort4 = 4 fp16 per lane).

__global__ __launch_bounds__(256) void layer_kernel(
        const ushort4* __restrict__ h16, const float4* __restrict__ x04,
        unsigned short* __restrict__ h_out,
        const int* __restrict__ rowptr, const int2* __restrict__ pack,
        const float* __restrict__ dinv,
        const float* __restrict__ W, float beta, int n) {
    __shared__ float Wsh[HID * HID];          // 16 KB
    __shared__ float4 zt[4][HID];             // 4 KB
    int tid = threadIdx.x;
    for (int i = tid; i < HID * HID / 4; i += 256)
        ((float4*)Wsh)[i] = ((const float4*)W)[i];
    __syncthreads();
    int lane = tid & 63, wave = tid >> 6;
    int g = lane >> 4;        // node within wave
    int c = lane & 15;        // ushort4 slot within row
    float omb = 1.0f - beta;

    for (int base = (blockIdx.x * 4 + wave) * 4; base < n; base += gridDim.x * 16) {
        // ---- phase 1: gather + residual ----
        int node = base + g;
        float4 acc = make_float4(0.f, 0.f, 0.f, 0.f);
        if (node < n) {
            float di = dinv[node];
            float d2 = di * di;
            ushort4 sv = h16[(size_t)node * 16 + c];
            acc.x = d2 * h2f(sv.x); acc.y = d2 * h2f(sv.y);
            acc.z = d2 * h2f(sv.z); acc.w = d2 * h2f(sv.w);
            int e0 = rowptr[node];
            int deg = rowptr[node + 1] - e0;
            int e = 0;
            for (; e + 4 <= deg; e += 4) {
                int2 p0 = pack[e0 + e + 0];
                int2 p1 = pack[e0 + e + 1];
                int2 p2 = pack[e0 + e + 2];
                int2 p3 = pack[e0 + e + 3];
                ushort4 v0 = h16[(size_t)p0.x * 16 + c];
                ushort4 v1 = h16[(size_t)p1.x * 16 + c];
                ushort4 v2 = h16[(size_t)p2.x * 16 + c];
                ushort4 v3 = h16[(size_t)p3.x * 16 + c];
                float n0 = __int_as_float(p0.y), n1 = __int_as_float(p1.y);
                float n2 = __int_as_float(p2.y), n3 = __int_as_float(p3.y);
                acc.x += n0 * h2f(v0.x) + n1 * h2f(v1.x) + n2 * h2f(v2.x) + n3 * h2f(v3.x);
                acc.y += n0 * h2f(v0.y) + n1 * h2f(v1.y) + n2 * h2f(v2.y) + n3 * h2f(v3.y);
                acc.z += n0 * h2f(v0.z) + n1 * h2f(v1.z) + n2 * h2f(v2.z) + n3 * h2f(v3.z);
                acc.w += n0 * h2f(v0.w) + n1 * h2f(v1.w) + n2 * h2f(v2.w) + n3 * h2f(v3.w);
            }
            for (; e < deg; e++) {
                int2 p = pack[e0 + e];
                ushort4 v = h16[(size_t)p.x * 16 + c];
                float nv = __int_as_float(p.y);
                acc.x += nv * h2f(v.x); acc.y += nv * h2f(v.y);
                acc.z += nv * h2f(v.z); acc.w += nv * h2f(v.w);
            }
            float4 x0v = x04[(size_t)node * 16 + c];
            acc.x = 0.5f * acc.x + 0.5f * x0v.x;   // ALPHA = 0.5
            acc.y = 0.5f * acc.y + 0.5f * x0v.y;
            acc.z = 0.5f * acc.z + 0.5f * x0v.z;
            acc.w = 0.5f * acc.w + 0.5f * x0v.w;
        }
        // ---- transpose z into zt (wave-internal) ----
        {
            float* zf = (float*)&zt[wave][0];
            zf[(4 * c + 0) * 4 + g] = acc.x;
            zf[(4 * c + 1) * 4 + g] = acc.y;
            zf[(4 * c + 2) * 4 + g] = acc.z;
            zf[(4 * c + 3) * 4 + g] = acc.w;
        }
        // ---- phase 2: matvec for 4 nodes, lane = output feature ----
        float4 mv = make_float4(0.f, 0.f, 0.f, 0.f);
        #pragma unroll 8
        for (int k = 0; k < HID; k++) {
            float4 zk = zt[wave][k];              // broadcast read
            float wk = Wsh[k * HID + lane];       // conflict-free
            mv.x += zk.x * wk; mv.y += zk.y * wk;
            mv.z += zk.z * wk; mv.w += zk.w * wk;
        }
        // ---- epilogue ----
        float4 zrow = zt[wave][lane];
        if (base + 0 < n) h_out[(size_t)(base + 0) * HID + lane] = f2h(fmaxf(omb * zrow.x + beta * mv.x, 0.f));
        if (base + 1 < n) h_out[(size_t)(base + 1) * HID + lane] = f2h(fmaxf(omb * zrow.y + beta * mv.y, 0.f));
        if (base + 2 < n) h_out[(size_t)(base + 2) * HID + lane] = f2h(fmaxf(omb * zrow.z + beta * mv.z, 0.f));
        if (base + 3 < n) h_out[(size_t)(base + 3) * HID + lane] = f2h(fmaxf(omb * zrow.w + beta * mv.w, 0.f));
    }
}

// ---------------- lin2 + log_softmax ----------------

__global__ __launch_bounds__(256) void out_kernel(const unsigned short* __restrict__ h,
        const float* __restrict__ W2, const float* __restrict__ b2,
        float* __restrict__ out, int n) {
    __shared__ float W2s[64 * 40];
    alignas(16) __shared__ float hs[4][64];
    int tid = threadIdx.x;
    for (int i = tid; i < 64 * 40; i += 256) W2s[i] = W2[i];
    __syncthreads();
    int lane = tid & 63, wave = tid >> 6;
    int c = (lane < 40) ? lane : 0;
    float wc[64];
    #pragma unroll
    for (int k = 0; k < 64; k++) wc[k] = W2s[k * 40 + c];
    float bias = b2[c];
    for (int i = blockIdx.x * 4 + wave; i < n; i += gridDim.x * 4) {
        hs[wave][lane] = h2f(h[(size_t)i * 64 + lane]);
        float o = bias;
        #pragma unroll
        for (int k4 = 0; k4 < 16; k4++) {
            float4 hb = *(float4*)&hs[wave][k4 * 4];
            o += hb.x * wc[k4 * 4 + 0] + hb.y * wc[k4 * 4 + 1]
               + hb.z * wc[k4 * 4 + 2] + hb.w * wc[k4 * 4 + 3];
        }
        float val = (lane < 40) ? o : -INFINITY;
        float m = val;
        #pragma unroll
        for (int d = 1; d < 64; d <<= 1) m = fmaxf(m, __shfl_xor(m, d, 64));
        float e = (lane < 40) ? expf(o - m) : 0.f;
        float s = e;
        #pragma unroll
        for (int d = 1; d < 64; d <<= 1) s += __shfl_xor(s, d, 64);
        if (lane < 40) out[(size_t)i * 40 + lane] = (o - m) - logf(s);
    }
}

__global__ void zero_out_kernel(float* __restrict__ out, int n) {
    int i = blockIdx.x * blockDim.x + threadIdx.x;
    if (i < n) out[i] = 0.f;
}

// ---------------- launcher ----------------

extern "C" void kernel_launch(void* const* d_in, const int* in_sizes, int n_in,
                              void* d_out, int out_size, void* d_ws, size_t ws_size,
                              hipStream_t stream) {
    const float* x    = (const float*)d_in[0];
    const int*   ei   = (const int*)d_in[1];     // int32
    const float* W1   = (const float*)d_in[2];
    const float* b1   = (const float*)d_in[3];
    const float* Wc   = (const float*)d_in[4];
    const float* W2   = (const float*)d_in[5];
    const float* b2   = (const float*)d_in[6];
    float* outp = (float*)d_out;

    const int N = in_sizes[0] / 512;         // 50000
    const int E = in_sizes[1] / 2;           // 800000
    const int L = in_sizes[4] / (HID * HID); // 64

    const int* src = ei;
    const int* dst = ei + E;
    const int NB_SCAN = (N + 1023) / 1024;   // 49

    size_t need = (size_t)N * HID * 4                 // x0b fp32
                + (size_t)N * HID * 2 * 2             // hA16, hB16
                + ((size_t)N * 3 + (N + 1) + (NB_SCAN + 1)) * 4
                + (size_t)E * 8;
    if (ws_size < need) {
        zero_out_kernel<<<(out_size + 255) / 256, 256, 0, stream>>>(outp, out_size);
        return;
    }
    char* p = (char*)d_ws;
    float* x0b  = (float*)p;               p += (size_t)N * HID * 4;
    unsigned short* hA16 = (unsigned short*)p;  p += (size_t)N * HID * 2;
    unsigned short* hB16 = (unsigned short*)p;  p += (size_t)N * HID * 2;
    float* dinv = (float*)p;               p += (size_t)N * 4;
    int2*  pack = (int2*)p;                p += (size_t)E * 8;
    int*   cnt  = (int*)p;                 p += (size_t)N * 4;
    int*   offs = (int*)p;                 p += (size_t)(N + 1) * 4;
    int*   cursor = (int*)p;               p += (size_t)N * 4;
    int*   bsum = (int*)p;                 p += (size_t)(NB_SCAN + 1) * 4;

    hipMemsetAsync(cnt, 0, (size_t)N * 4, stream);
    hipMemsetAsync(cursor, 0, (size_t)N * 4, stream);

    count_kernel<<<(E + 255) / 256, 256, 0, stream>>>(dst, cnt, E, N);
    dinv_kernel<<<(N + 255) / 256, 256, 0, stream>>>(cnt, dinv, N);
    scanA_kernel<<<NB_SCAN, 1024, 0, stream>>>(cnt, offs, bsum, N);
    scanB_kernel<<<1, 1024, 0, stream>>>(bsum, NB_SCAN);
    scanC_kernel<<<NB_SCAN, 1024, 0, stream>>>(offs, bsum, N, NB_SCAN);
    fill_kernel<<<(E + 255) / 256, 256, 0, stream>>>(src, dst, offs, cursor, dinv,
                                                     pack, E, N);

    lin1_kernel<<<(N + 63) / 64, 256, 0, stream>>>(x, W1, b1, x0b, hA16, N);

    unsigned short* cur_in = hA16;
    unsigned short* cur_out = hB16;
    for (int l = 0; l < L; l++) {
        float beta = log1pf(1.0f / (float)(l + 1));
        layer_kernel<<<2048, 256, 0, stream>>>((const ushort4*)cur_in, (const float4*)x0b,
                                               cur_out, offs, pack, dinv,
                                               Wc + (size_t)l * HID * HID, beta, N);
        unsigned short* nxt = cur_in;
        cur_in = cur_out;
        cur_out = nxt;
    }

    out_kernel<<<1024, 256, 0, stream>>>(cur_in, W2, b2, outp, N);
}